// Round 1
// baseline (493.307 us; speedup 1.0000x reference)
//
#include <hip/hip_runtime.h>
#include <stdint.h>

typedef unsigned short ushort_t;
typedef short shortx8 __attribute__((ext_vector_type(8)));       // 8 bf16 in 4 VGPRs
typedef float floatx4 __attribute__((ext_vector_type(4)));
typedef unsigned short ushortx8 __attribute__((ext_vector_type(8)));

__device__ __forceinline__ unsigned short f2bf(float f) {
  union { float f; unsigned int u; } v; v.f = f;
  unsigned int u = v.u;
  return (unsigned short)((u + 0x7fffu + ((u >> 16) & 1u)) >> 16);  // RNE
}

__device__ __forceinline__ void gload_lds16(const void* g, void* l) {
  __builtin_amdgcn_global_load_lds(
      (const __attribute__((address_space(1))) unsigned int*)g,
      (__attribute__((address_space(3))) unsigned int*)l, 16, 0, 0);
}

// ---------------- prep kernels ----------------

__global__ void cvt_f32_bf16_k(const float* __restrict__ in, ushort_t* __restrict__ out, int n8) {
  int i = blockIdx.x * blockDim.x + threadIdx.x;
  if (i >= n8) return;
  const float4* p = (const float4*)in;
  float4 a = p[i * 2], b = p[i * 2 + 1];
  ushortx8 v;
  v[0] = f2bf(a.x); v[1] = f2bf(a.y); v[2] = f2bf(a.z); v[3] = f2bf(a.w);
  v[4] = f2bf(b.x); v[5] = f2bf(b.y); v[6] = f2bf(b.z); v[7] = f2bf(b.w);
  ((ushortx8*)out)[i] = v;
}

// out[n*K + k] = bf16(in[k*N + n])   (weights are tiny; L2 absorbs strided reads)
template <int K, int N>
__global__ void transpose_cvt_k(const float* __restrict__ in, ushort_t* __restrict__ out) {
  int idx = blockIdx.x * blockDim.x + threadIdx.x;
  if (idx >= N * K) return;
  int n = idx / K, k = idx - n * K;
  out[idx] = f2bf(in[k * N + n]);
}

// ---------------- m97-style GEMM ----------------
// C[M,NOUT] = relu(A[M,K] @ B[K,NOUT] + bias), B given transposed as BT[NOUT,K].
// MODE 0: store bf16 C.  MODE 1: + pos tail (W1 rows 256..258), store bf16 C.
// MODE 2: fused segment-max (segments of 4096 rows) -> pool[32, NOUT] fp32 via atomicMax.
template <int K, int NOUT, int MODE>
__global__ __launch_bounds__(256, 2) void gemm_kernel(
    const ushort_t* __restrict__ A, const ushort_t* __restrict__ BT,
    const float* __restrict__ bias, ushort_t* __restrict__ C,
    const float* __restrict__ pos, const float* __restrict__ W1tail,
    float* __restrict__ pool) {
  __shared__ __align__(16) ushort_t As[128 * 64];
  __shared__ __align__(16) ushort_t Bs[128 * 64];

  const int n0 = blockIdx.x * 128;
  const int m0 = blockIdx.y * 128;
  const int tid = threadIdx.x;
  const int w = tid >> 6;
  const int l = tid & 63;
  const int wm = w >> 1, wn = w & 1;
  const int lane16 = l & 15, lq = l >> 4;

  floatx4 acc[4][4] = {};

  const int estart = w * 512 + l * 8;
  for (int k0 = 0; k0 < K; k0 += 64) {
#pragma unroll
    for (int r = 0; r < 4; ++r) {
      int e = r * 2048 + estart;
      int row = e >> 6, col = e & 63;
      gload_lds16(A + (size_t)(m0 + row) * K + k0 + col, As + r * 2048 + w * 512);
      gload_lds16(BT + (size_t)(n0 + row) * K + k0 + col, Bs + r * 2048 + w * 512);
    }
    __syncthreads();
#pragma unroll
    for (int kk = 0; kk < 2; ++kk) {
      shortx8 af[4], bfr[4];
#pragma unroll
      for (int i = 0; i < 4; ++i)
        af[i] = *(const shortx8*)(As + (wm * 64 + i * 16 + lane16) * 64 + kk * 32 + lq * 8);
#pragma unroll
      for (int j = 0; j < 4; ++j)
        bfr[j] = *(const shortx8*)(Bs + (wn * 64 + j * 16 + lane16) * 64 + kk * 32 + lq * 8);
#pragma unroll
      for (int i = 0; i < 4; ++i)
#pragma unroll
        for (int j = 0; j < 4; ++j)
          acc[i][j] = __builtin_amdgcn_mfma_f32_16x16x32_bf16(af[i], bfr[j], acc[i][j], 0, 0, 0);
    }
    __syncthreads();
  }

  float bv[4];
#pragma unroll
  for (int j = 0; j < 4; ++j) bv[j] = bias[n0 + wn * 64 + j * 16 + lane16];

  if (MODE == 2) {
    const int seg = m0 >> 12;  // 4096 rows per segment; 128-row tile never straddles
#pragma unroll
    for (int j = 0; j < 4; ++j) {
      float vmax = 0.0f;  // relu identity: max(0, max_pre) == max over relu'd rows
#pragma unroll
      for (int i = 0; i < 4; ++i)
#pragma unroll
        for (int r = 0; r < 4; ++r) vmax = fmaxf(vmax, acc[i][j][r] + bv[j]);
      vmax = fmaxf(vmax, __shfl_xor(vmax, 16, 64));
      vmax = fmaxf(vmax, __shfl_xor(vmax, 32, 64));
      if (l < 16) {
        int n = n0 + wn * 64 + j * 16 + lane16;
        atomicMax((int*)(pool + (size_t)seg * NOUT + n), __float_as_int(vmax));
      }
    }
  } else {
#pragma unroll
    for (int i = 0; i < 4; ++i) {
#pragma unroll
      for (int r = 0; r < 4; ++r) {
        int m = m0 + wm * 64 + i * 16 + lq * 4 + r;
        float p0 = 0.f, p1 = 0.f, p2 = 0.f;
        if (MODE == 1) { p0 = pos[m * 3 + 0]; p1 = pos[m * 3 + 1]; p2 = pos[m * 3 + 2]; }
#pragma unroll
        for (int j = 0; j < 4; ++j) {
          int n = n0 + wn * 64 + j * 16 + lane16;
          float v = acc[i][j][r] + bv[j];
          if (MODE == 1) v += p0 * W1tail[n] + p1 * W1tail[256 + n] + p2 * W1tail[512 + n];
          v = fmaxf(v, 0.0f);
          C[(size_t)m * NOUT + n] = f2bf(v);
        }
      }
    }
  }
}

// ---------------- launch ----------------

extern "C" void kernel_launch(void* const* d_in, const int* in_sizes, int n_in,
                              void* d_out, int out_size, void* d_ws, size_t ws_size,
                              hipStream_t stream) {
  const float* x   = (const float*)d_in[0];
  const float* pos = (const float*)d_in[1];
  // d_in[2] = batch (int32) — unused: sorted equal segments of 4096 (setup-guaranteed)
  const float* W1 = (const float*)d_in[3];
  const float* b1 = (const float*)d_in[4];
  const float* W2 = (const float*)d_in[5];
  const float* b2 = (const float*)d_in[6];
  const float* W3 = (const float*)d_in[7];
  const float* b3 = (const float*)d_in[8];
  float* out = (float*)d_out;

  const int M = in_sizes[0] / 256;  // 131072

  // ws layout: [0,134MB) Xb (first 67MB, dead after gemm1) then reused by H2;
  //            [134,201MB) H1; weights after.
  char* ws = (char*)d_ws;
  ushort_t* Xb  = (ushort_t*)ws;                               // [M,256] bf16
  ushort_t* H2  = (ushort_t*)ws;                               // [M,512] bf16 (overlaps Xb)
  ushort_t* H1  = (ushort_t*)(ws + (size_t)M * 512 * 2);       // [M,256] bf16
  ushort_t* W1T = (ushort_t*)(ws + (size_t)M * 512 * 2 + (size_t)M * 256 * 2);
  ushort_t* W2T = W1T + 256 * 256;
  ushort_t* W3T = W2T + 512 * 256;

  hipMemsetAsync(d_out, 0, (size_t)out_size * sizeof(float), stream);

  int n8 = M * 256 / 8;
  cvt_f32_bf16_k<<<(n8 + 255) / 256, 256, 0, stream>>>(x, Xb, n8);
  transpose_cvt_k<256, 256><<<(256 * 256 + 255) / 256, 256, 0, stream>>>(W1, W1T);
  transpose_cvt_k<256, 512><<<(512 * 256 + 255) / 256, 256, 0, stream>>>(W2, W2T);
  transpose_cvt_k<512, 1024><<<(1024 * 512 + 255) / 256, 256, 0, stream>>>(W3, W3T);

  gemm_kernel<256, 256, 1><<<dim3(2, M / 128), 256, 0, stream>>>(
      Xb, W1T, b1, H1, pos, W1 + 256 * 256, nullptr);
  gemm_kernel<256, 512, 0><<<dim3(4, M / 128), 256, 0, stream>>>(
      H1, W2T, b2, H2, nullptr, nullptr, nullptr);
  gemm_kernel<512, 1024, 2><<<dim3(8, M / 128), 256, 0, stream>>>(
      H2, W3T, b3, nullptr, nullptr, nullptr, out);
}

// Round 2
// 470.810 us; speedup vs baseline: 1.0478x; 1.0478x over previous
//
#include <hip/hip_runtime.h>
#include <stdint.h>

typedef unsigned short ushort_t;
typedef short shortx8 __attribute__((ext_vector_type(8)));       // 8 bf16 in 4 VGPRs
typedef float floatx4 __attribute__((ext_vector_type(4)));
typedef unsigned short ushortx8 __attribute__((ext_vector_type(8)));

__device__ __forceinline__ unsigned short f2bf(float f) {
  union { float f; unsigned int u; } v; v.f = f;
  unsigned int u = v.u;
  return (unsigned short)((u + 0x7fffu + ((u >> 16) & 1u)) >> 16);  // RNE
}

__device__ __forceinline__ void gload_lds16(const void* g, void* l) {
  __builtin_amdgcn_global_load_lds(
      (const __attribute__((address_space(1))) unsigned int*)g,
      (__attribute__((address_space(3))) unsigned int*)l, 16, 0, 0);
}

// ---------------- prep kernels ----------------

__global__ void cvt_f32_bf16_k(const float* __restrict__ in, ushort_t* __restrict__ out, int n8) {
  int i = blockIdx.x * blockDim.x + threadIdx.x;
  if (i >= n8) return;
  const float4* p = (const float4*)in;
  float4 a = p[i * 2], b = p[i * 2 + 1];
  ushortx8 v;
  v[0] = f2bf(a.x); v[1] = f2bf(a.y); v[2] = f2bf(a.z); v[3] = f2bf(a.w);
  v[4] = f2bf(b.x); v[5] = f2bf(b.y); v[6] = f2bf(b.z); v[7] = f2bf(b.w);
  ((ushortx8*)out)[i] = v;
}

// out[n*K + k] = bf16(in[k*N + n])   (weights are tiny; L2 absorbs strided reads)
template <int K, int N>
__global__ void transpose_cvt_k(const float* __restrict__ in, ushort_t* __restrict__ out) {
  int idx = blockIdx.x * blockDim.x + threadIdx.x;
  if (idx >= N * K) return;
  int n = idx / K, k = idx - n * K;
  out[idx] = f2bf(in[k * N + n]);
}

// ---------------- m97-style GEMM, XOR-swizzled LDS ----------------
// C[M,NOUT] = relu(A[M,K] @ B[K,NOUT] + bias), B given transposed as BT[NOUT,K].
// LDS layout: tile row r (128 B = 8 granules of 16 B); granule slot p holds
// global granule p ^ (r&7). global_load_lds writes lane l -> base + l*16, so
// lane l (row l>>3, slot l&7) fetches global granule (l&7)^(l>>3). Fragment
// reads XOR the granule index with (row&7) -> 16 lanes spread over 8 bank
// phases (2-way = free) instead of 16-way conflicts.
// MODE 0: store bf16 C.  MODE 1: + pos tail (W1 rows 256..258), store bf16 C.
// MODE 2: fused segment-max (segments of 4096 rows) -> pool[32, NOUT] fp32 via atomicMax.
template <int K, int NOUT, int MODE>
__global__ __launch_bounds__(256, 2) void gemm_kernel(
    const ushort_t* __restrict__ A, const ushort_t* __restrict__ BT,
    const float* __restrict__ bias, ushort_t* __restrict__ C,
    const float* __restrict__ pos, const float* __restrict__ W1tail,
    float* __restrict__ pool) {
  __shared__ __align__(16) ushort_t As[128 * 64];
  __shared__ __align__(16) ushort_t Bs[128 * 64];

  // grid: x = m-tile (fast), y = n-tile  => bid%8 = m%8: the n-blocks sharing
  // an A row-tile land on the same XCD (L2-resident A, one fabric fetch).
  const int m0 = blockIdx.x * 128;
  const int n0 = blockIdx.y * 128;
  const int tid = threadIdx.x;
  const int w = tid >> 6;
  const int l = tid & 63;
  const int wm = w >> 1, wn = w & 1;
  const int lane16 = l & 15, lq = l >> 4;
  const int s7 = lane16 & 7;

  // staging decomposition: 16 chunks of 1 KB (8 rows x 128 B) per operand
  const int srow = l >> 3;          // row within chunk
  const int sg = (l & 7) ^ srow;    // swizzled source granule (elems*8)

  floatx4 acc[4][4] = {};

  for (int k0 = 0; k0 < K; k0 += 64) {
#pragma unroll
    for (int r = 0; r < 4; ++r) {
      const int c = r * 4 + w;            // chunk 0..15
      const int row = c * 8 + srow;       // tile row 0..127
      gload_lds16(A + (size_t)(m0 + row) * K + k0 + sg * 8, As + c * 512);
      gload_lds16(BT + (size_t)(n0 + row) * K + k0 + sg * 8, Bs + c * 512);
    }
    __syncthreads();
#pragma unroll
    for (int kk = 0; kk < 2; ++kk) {
      shortx8 af[4], bfr[4];
#pragma unroll
      for (int i = 0; i < 4; ++i) {
        const int row = wm * 64 + i * 16 + lane16;
        af[i] = *(const shortx8*)(As + row * 64 + ((kk * 4 + lq) ^ s7) * 8);
      }
#pragma unroll
      for (int j = 0; j < 4; ++j) {
        const int row = wn * 64 + j * 16 + lane16;
        bfr[j] = *(const shortx8*)(Bs + row * 64 + ((kk * 4 + lq) ^ s7) * 8);
      }
#pragma unroll
      for (int i = 0; i < 4; ++i)
#pragma unroll
        for (int j = 0; j < 4; ++j)
          acc[i][j] = __builtin_amdgcn_mfma_f32_16x16x32_bf16(af[i], bfr[j], acc[i][j], 0, 0, 0);
    }
    __syncthreads();
  }

  float bv[4];
#pragma unroll
  for (int j = 0; j < 4; ++j) bv[j] = bias[n0 + wn * 64 + j * 16 + lane16];

  if (MODE == 2) {
    const int seg = m0 >> 12;  // 4096 rows per segment; 128-row tile never straddles
#pragma unroll
    for (int j = 0; j < 4; ++j) {
      float vmax = 0.0f;  // relu identity: max(0, max_pre) == max over relu'd rows
#pragma unroll
      for (int i = 0; i < 4; ++i)
#pragma unroll
        for (int r = 0; r < 4; ++r) vmax = fmaxf(vmax, acc[i][j][r] + bv[j]);
      vmax = fmaxf(vmax, __shfl_xor(vmax, 16, 64));
      vmax = fmaxf(vmax, __shfl_xor(vmax, 32, 64));
      if (l < 16) {
        int n = n0 + wn * 64 + j * 16 + lane16;
        atomicMax((int*)(pool + (size_t)seg * NOUT + n), __float_as_int(vmax));
      }
    }
  } else {
#pragma unroll
    for (int i = 0; i < 4; ++i) {
#pragma unroll
      for (int r = 0; r < 4; ++r) {
        int m = m0 + wm * 64 + i * 16 + lq * 4 + r;
        float p0 = 0.f, p1 = 0.f, p2 = 0.f;
        if (MODE == 1) { p0 = pos[m * 3 + 0]; p1 = pos[m * 3 + 1]; p2 = pos[m * 3 + 2]; }
#pragma unroll
        for (int j = 0; j < 4; ++j) {
          int n = n0 + wn * 64 + j * 16 + lane16;
          float v = acc[i][j][r] + bv[j];
          if (MODE == 1) v += p0 * W1tail[n] + p1 * W1tail[256 + n] + p2 * W1tail[512 + n];
          v = fmaxf(v, 0.0f);
          C[(size_t)m * NOUT + n] = f2bf(v);
        }
      }
    }
  }
}

// ---------------- launch ----------------

extern "C" void kernel_launch(void* const* d_in, const int* in_sizes, int n_in,
                              void* d_out, int out_size, void* d_ws, size_t ws_size,
                              hipStream_t stream) {
  const float* x   = (const float*)d_in[0];
  const float* pos = (const float*)d_in[1];
  // d_in[2] = batch (int32) — unused: sorted equal segments of 4096 (setup-guaranteed)
  const float* W1 = (const float*)d_in[3];
  const float* b1 = (const float*)d_in[4];
  const float* W2 = (const float*)d_in[5];
  const float* b2 = (const float*)d_in[6];
  const float* W3 = (const float*)d_in[7];
  const float* b3 = (const float*)d_in[8];
  float* out = (float*)d_out;

  const int M = in_sizes[0] / 256;  // 131072

  // ws layout: [0,134MB) Xb (first 67MB, dead after gemm1) then reused by H2;
  //            [134,201MB) H1; weights after.
  char* ws = (char*)d_ws;
  ushort_t* Xb  = (ushort_t*)ws;                               // [M,256] bf16
  ushort_t* H2  = (ushort_t*)ws;                               // [M,512] bf16 (overlaps Xb)
  ushort_t* H1  = (ushort_t*)(ws + (size_t)M * 512 * 2);       // [M,256] bf16
  ushort_t* W1T = (ushort_t*)(ws + (size_t)M * 512 * 2 + (size_t)M * 256 * 2);
  ushort_t* W2T = W1T + 256 * 256;
  ushort_t* W3T = W2T + 512 * 256;

  hipMemsetAsync(d_out, 0, (size_t)out_size * sizeof(float), stream);

  int n8 = M * 256 / 8;
  cvt_f32_bf16_k<<<(n8 + 255) / 256, 256, 0, stream>>>(x, Xb, n8);
  transpose_cvt_k<256, 256><<<(256 * 256 + 255) / 256, 256, 0, stream>>>(W1, W1T);
  transpose_cvt_k<256, 512><<<(512 * 256 + 255) / 256, 256, 0, stream>>>(W2, W2T);
  transpose_cvt_k<512, 1024><<<(1024 * 512 + 255) / 256, 256, 0, stream>>>(W3, W3T);

  gemm_kernel<256, 256, 1><<<dim3(M / 128, 2), 256, 0, stream>>>(
      Xb, W1T, b1, H1, pos, W1 + 256 * 256, nullptr);
  gemm_kernel<256, 512, 0><<<dim3(M / 128, 4), 256, 0, stream>>>(
      H1, W2T, b2, H2, nullptr, nullptr, nullptr);
  gemm_kernel<512, 1024, 2><<<dim3(M / 128, 8), 256, 0, stream>>>(
      H2, W3T, b3, nullptr, nullptr, nullptr, out);
}